// Round 1
// baseline (201.674 us; speedup 1.0000x reference)
//
#include <hip/hip_runtime.h>

// Problem constants (from reference)
#define B_ 32
#define T_ 256
#define J_ 25
#define C_ 256
#define H_ 64
#define NBT (B_*T_)          // 8192 blocks
#define SCALE 0.125f         // 1/sqrt(64)

typedef __attribute__((ext_vector_type(8))) short short8;   // 8 bf16 (4 VGPRs)
typedef __attribute__((ext_vector_type(4))) float f32x4;    // MFMA accumulator

__device__ __forceinline__ ushort f2b(float f) {
  union { float f; unsigned u; } v; v.f = f;
  unsigned r = v.u + 0x7FFFu + ((v.u >> 16) & 1u);  // round-to-nearest-even
  return (ushort)(r >> 16);
}
__device__ __forceinline__ float b2f(ushort u) {
  union { unsigned u; float f; } v; v.u = ((unsigned)u) << 16; return v.f;
}

// ---------------------------------------------------------------------------
// Pre-pack weights into bf16 B-fragment order in d_ws.
// wpack layout: frag(nt 0..23, ks 0..7): [((nt*8+ks)*64 + lane)*8 + e]
//   holds W[k = ks*32 + (lane>>4)*8 + e][n = nt*16 + (lane&15)]
//   where W = concat cols: n<64 -> Wq, n<128 -> Wk, else Wv (n-128).
// apack: frag(nt 0..1, ks 0..1) same scheme over attn_w [64][25] (zero-pad n>=25).
// ---------------------------------------------------------------------------
__global__ void prepack_kernel(const float* __restrict__ Wq, const float* __restrict__ Wk,
                               const float* __restrict__ Wv, const float* __restrict__ attn_w,
                               ushort* __restrict__ wpack, ushort* __restrict__ apack) {
  int idx = blockIdx.x * 256 + threadIdx.x;
  if (idx >= 98304 + 2048) return;
  if (idx < 98304) {
    int e  = idx & 7;
    int l  = (idx >> 3) & 63;
    int ks = (idx >> 9) & 7;
    int nt = idx >> 12;                       // 0..23
    int k = ks * 32 + (l >> 4) * 8 + e;       // 0..255
    int n = nt * 16 + (l & 15);               // 0..383
    float v;
    if (n < H_)            v = Wq[k * H_ + n];
    else if (n < 2 * H_)   v = Wk[k * H_ + (n - H_)];
    else                   v = Wv[k * C_ + (n - 2 * H_)];
    wpack[idx] = f2b(v);
  } else {
    int j  = idx - 98304;
    int e  = j & 7;
    int l  = (j >> 3) & 63;
    int ks = (j >> 9) & 1;
    int nt = j >> 10;                          // 0..1
    int k = ks * 32 + (l >> 4) * 8 + e;        // 0..63
    int n = nt * 16 + (l & 15);                // 0..31
    apack[j] = (n < J_) ? f2b(attn_w[k * J_ + n]) : (ushort)0;
  }
}

// ---------------------------------------------------------------------------
// Fused kernel: one block per (b,t).  256 threads = 4 waves.
// ---------------------------------------------------------------------------
__global__ __launch_bounds__(256) void fused_attn_kernel(
    const float* __restrict__ x, const float* __restrict__ bias_mat,
    const float* __restrict__ bq, const float* __restrict__ bk,
    const float* __restrict__ bv, const float* __restrict__ att_bias,
    const float* __restrict__ ln_g, const float* __restrict__ ln_b,
    const ushort* __restrict__ wpack, const ushort* __restrict__ apack,
    float* __restrict__ out)
{
  // LDS (all bf16 tiles XOR-swizzled to avoid 16-way bank conflicts on b128 reads)
  __shared__ __align__(16) ushort XS[32 * 256];  // x bf16, rows 25..31 zero
  __shared__ __align__(16) ushort QS[32 * 64];   // Q
  __shared__ __align__(16) ushort KS[32 * 64];   // K (row=j, col=h) -> B-frag for Q@K^T
  __shared__ __align__(16) ushort VT[256 * 32];  // V transposed [c][j]; reused later as y[32][256]
  __shared__ __align__(16) ushort PS[32 * 32];   // softmax probs bf16
  __shared__ __align__(16) float  SS[32 * 36];   // scores fp32 (stride 36 avoids overlap/conflicts)
  __shared__ float GS[256], BS[256];             // ln_g, ln_b

  const int t    = threadIdx.x;
  const int blk  = blockIdx.x;
  const int lane = t & 63;
  const int w    = t >> 6;
  const int l15  = lane & 15;
  const int lhi  = lane >> 4;

  const float* xg = x + (size_t)blk * (J_ * C_);

  // ---- stage x -> bf16 LDS (swizzled), cache ln params ----
  GS[t] = ln_g[t];
  BS[t] = ln_b[t];
  for (int i = 0; i < J_; ++i) {
    float f = xg[i * C_ + t];
    XS[i * C_ + (t ^ ((i & 7) << 3))] = f2b(f);
  }
  for (int i = J_; i < 32; ++i) XS[i * C_ + (t ^ ((i & 7) << 3))] = 0;
  __syncthreads();

  // ---- cache A-fragments of X: 2 Mtiles x 8 ksteps ----
  short8 af[2][8];
#pragma unroll
  for (int mt = 0; mt < 2; ++mt) {
    int row = mt * 16 + l15;
#pragma unroll
    for (int ks = 0; ks < 8; ++ks)
      af[mt][ks] = *reinterpret_cast<const short8*>(
          &XS[row * C_ + ((ks * 32 + lhi * 8) ^ ((row & 7) << 3))]);
  }

  // ---- projections: [32x256] @ [256x384] -> Q|K|V ----
  // wave w handles Ntiles {w, w+4, ..., w+20}
#pragma unroll
  for (int i = 0; i < 6; ++i) {
    int nt = w + 4 * i;
    f32x4 acc0 = {0.f, 0.f, 0.f, 0.f};
    f32x4 acc1 = {0.f, 0.f, 0.f, 0.f};
    const ushort* bp = wpack + (size_t)nt * 4096 + lane * 8;
#pragma unroll
    for (int ks = 0; ks < 8; ++ks) {
      short8 bfr = *reinterpret_cast<const short8*>(bp + ks * 512);
      acc0 = __builtin_amdgcn_mfma_f32_16x16x32_bf16(af[0][ks], bfr, acc0, 0, 0, 0);
      acc1 = __builtin_amdgcn_mfma_f32_16x16x32_bf16(af[1][ks], bfr, acc1, 0, 0, 0);
    }
    int n = nt * 16 + l15;
    float bias = (n < H_) ? bq[n] : (n < 2 * H_) ? bk[n - H_] : bv[n - 2 * H_];
#pragma unroll
    for (int mt = 0; mt < 2; ++mt) {
      f32x4 a = mt ? acc1 : acc0;
#pragma unroll
      for (int r = 0; r < 4; ++r) {
        int row = mt * 16 + lhi * 4 + r;
        ushort u = f2b(a[r] + bias);
        if (n < H_)            QS[row * 64 + (n ^ ((row & 7) << 3))] = u;
        else if (n < 2 * H_)   KS[row * 64 + ((n - H_) ^ ((row & 7) << 3))] = u;
        else { int c = n - 2 * H_; VT[c * 32 + (row ^ ((c & 3) << 3))] = u; }
      }
    }
  }
  __syncthreads();

  // ---- scores: S = Q@attn_w + att_bias + (Q@K^T)*scale + bias_mat ----
  // 4 tiles (2 Mtiles x 2 Ntiles), one per wave
  {
    int mt = w >> 1, nt = w & 1;
    int arow = mt * 16 + l15;
    short8 qa[2];
#pragma unroll
    for (int ks = 0; ks < 2; ++ks)
      qa[ks] = *reinterpret_cast<const short8*>(
          &QS[arow * 64 + ((ks * 32 + lhi * 8) ^ ((arow & 7) << 3))]);
    f32x4 accW = {0.f, 0.f, 0.f, 0.f};
    f32x4 accD = {0.f, 0.f, 0.f, 0.f};
    int nrow = nt * 16 + l15;
#pragma unroll
    for (int ks = 0; ks < 2; ++ks) {
      short8 bw = *reinterpret_cast<const short8*>(&apack[(nt * 2 + ks) * 512 + lane * 8]);
      accW = __builtin_amdgcn_mfma_f32_16x16x32_bf16(qa[ks], bw, accW, 0, 0, 0);
      short8 bkf = *reinterpret_cast<const short8*>(
          &KS[nrow * 64 + ((ks * 32 + lhi * 8) ^ ((nrow & 7) << 3))]);
      accD = __builtin_amdgcn_mfma_f32_16x16x32_bf16(qa[ks], bkf, accD, 0, 0, 0);
    }
#pragma unroll
    for (int r = 0; r < 4; ++r) {
      int row = mt * 16 + lhi * 4 + r;
      int col = nt * 16 + l15;
      int br = row < J_ ? row : J_ - 1;
      int bc = col < J_ ? col : J_ - 1;
      SS[row * 36 + col] = accW[r] + SCALE * accD[r] + bias_mat[br * 25 + bc] + att_bias[bc];
    }
  }
  __syncthreads();

  // ---- softmax over k (25 real cols); write P bf16 (padded cols/rows = 0) ----
  if (t < 32) {
    int j = t;
    if (j < J_) {
      float m = -1e30f;
#pragma unroll
      for (int k = 0; k < J_; ++k) m = fmaxf(m, SS[j * 36 + k]);
      float p[J_];
      float sum = 0.f;
#pragma unroll
      for (int k = 0; k < J_; ++k) { p[k] = __expf(SS[j * 36 + k] - m); sum += p[k]; }
      float inv = 1.f / sum;
#pragma unroll
      for (int k = 0; k < J_; ++k) PS[j * 32 + (k ^ ((j & 3) << 3))] = f2b(p[k] * inv);
#pragma unroll
      for (int k = J_; k < 32; ++k) PS[j * 32 + (k ^ ((j & 3) << 3))] = 0;
    } else {
#pragma unroll
      for (int k = 0; k < 32; ++k) PS[j * 32 + (k ^ ((j & 3) << 3))] = 0;
    }
  }
  __syncthreads();

  // ---- PV: attended = P @ V, + residual x ----
  int mt = w >> 1;
  int prow = mt * 16 + l15;
  short8 pa = *reinterpret_cast<const short8*>(
      &PS[prow * 32 + ((lhi * 8) ^ ((prow & 3) << 3))]);
  float yv[8][4];
#pragma unroll
  for (int i = 0; i < 8; ++i) {
    int nt = (w & 1) * 8 + i;
    int c = nt * 16 + l15;
    short8 vb = *reinterpret_cast<const short8*>(
        &VT[c * 32 + ((lhi * 8) ^ ((c & 3) << 3))]);
    f32x4 z = {0.f, 0.f, 0.f, 0.f};
    f32x4 acc = __builtin_amdgcn_mfma_f32_16x16x32_bf16(pa, vb, z, 0, 0, 0);
#pragma unroll
    for (int r = 0; r < 4; ++r) {
      int row = mt * 16 + lhi * 4 + r;
      yv[i][r] = acc[r] + b2f(XS[row * C_ + (c ^ ((row & 7) << 3))]);
    }
  }
  __syncthreads();  // everyone done reading VT / XS before VT is reused for y

  // ---- stage y bf16 into VT buffer (now treated as y[32][256], swizzled) ----
#pragma unroll
  for (int i = 0; i < 8; ++i) {
    int nt = (w & 1) * 8 + i;
    int c = nt * 16 + l15;
#pragma unroll
    for (int r = 0; r < 4; ++r) {
      int row = mt * 16 + lhi * 4 + r;
      VT[row * C_ + (c ^ ((row & 7) << 3))] = f2b(yv[i][r]);
    }
  }
  __syncthreads();

  // ---- LayerNorm + store: 8 threads per row ----
  {
    int row = t >> 3, sub = t & 7;
    short8 ych[4];
    float s1 = 0.f, s2 = 0.f;
#pragma unroll
    for (int i = 0; i < 4; ++i) {
      int cb = sub * 32 + i * 8;
      ych[i] = *reinterpret_cast<const short8*>(
          &VT[row * C_ + (cb ^ ((row & 7) << 3))]);
#pragma unroll
      for (int e = 0; e < 8; ++e) {
        float f = b2f((ushort)ych[i][e]);
        s1 += f; s2 += f * f;
      }
    }
    s1 += __shfl_xor(s1, 1, 8); s2 += __shfl_xor(s2, 1, 8);
    s1 += __shfl_xor(s1, 2, 8); s2 += __shfl_xor(s2, 2, 8);
    s1 += __shfl_xor(s1, 4, 8); s2 += __shfl_xor(s2, 4, 8);
    float mu   = s1 * (1.f / 256.f);
    float var  = s2 * (1.f / 256.f) - mu * mu;
    float rstd = rsqrtf(var + 1e-5f);
    if (row < J_) {
      float* ob = out + (size_t)blk * (J_ * C_) + row * C_;
#pragma unroll
      for (int i = 0; i < 4; ++i) {
        int cb = sub * 32 + i * 8;
        float o[8];
#pragma unroll
        for (int e = 0; e < 8; ++e) {
          int c = cb + e;
          o[e] = (b2f((ushort)ych[i][e]) - mu) * rstd * GS[c] + BS[c];
        }
        float4 o0 = {o[0], o[1], o[2], o[3]};
        float4 o1 = {o[4], o[5], o[6], o[7]};
        *reinterpret_cast<float4*>(ob + cb) = o0;
        *reinterpret_cast<float4*>(ob + cb + 4) = o1;
      }
    }
  }
}

// ---------------------------------------------------------------------------
extern "C" void kernel_launch(void* const* d_in, const int* in_sizes, int n_in,
                              void* d_out, int out_size, void* d_ws, size_t ws_size,
                              hipStream_t stream) {
  const float* x        = (const float*)d_in[0];
  const float* bias_mat = (const float*)d_in[1];
  const float* Wq       = (const float*)d_in[2];
  const float* bq       = (const float*)d_in[3];
  const float* Wk       = (const float*)d_in[4];
  const float* bk       = (const float*)d_in[5];
  const float* Wv       = (const float*)d_in[6];
  const float* bv       = (const float*)d_in[7];
  const float* attn_w   = (const float*)d_in[8];
  const float* att_bias = (const float*)d_in[9];
  const float* ln_g     = (const float*)d_in[10];
  const float* ln_b     = (const float*)d_in[11];
  float* out = (float*)d_out;

  ushort* wpack = (ushort*)d_ws;          // 98304 bf16 = 192 KiB
  ushort* apack = wpack + 98304;          // 2048 bf16  = 4 KiB   (ws usage ~200.7 KB)

  prepack_kernel<<<392, 256, 0, stream>>>(Wq, Wk, Wv, attn_w, wpack, apack);
  fused_attn_kernel<<<NBT, 256, 0, stream>>>(x, bias_mat, bq, bk, bv, att_bias,
                                             ln_g, ln_b, wpack, apack, out);
}